// Round 2
// baseline (956.652 us; speedup 1.0000x reference)
//
#include <hip/hip_runtime.h>

// CTRNN forward, B=256 T=2048 D=32 H=64. ALL tensors fp32.
// r5 changes vs 677us kernel:
//  (A) xproj: 16KB tile (128 rows) -> 8 blocks/CU resident (was 5 with 32KB);
//      FMAs packed as v_pk_fma_f32 (halves VALU issue). Bit-identical math.
//  (B) recur: readlane broadcast (issue-bound on VALU, ~450cy/step) replaced
//      by LDS-crossbar broadcast: 1 ds_bpermute half-swap + 2 cndmask build
//      z_lo[l]=h[l&31], z_hi[l]=h[32|(l&31)]; 64 ds_swizzle (and=0,or=c)
//      broadcast each h[c] to all lanes. No LDS array access (no 120cy bank
//      latency), broadcast runs on LDS pipe concurrent with VALU FMA chain.
//      Per-lane accumulation order bit-identical to passing kernel.

#define Bb 256
#define Tt 2048
#define Dd 32
#define Hh 64

typedef float v2f __attribute__((ext_vector_type(2)));

static constexpr float ALPHA = (float)(16.67 / 40.0);
static constexpr float OMA   = 1.0f - ALPHA;

static __device__ inline v2f vfma2(v2f a, v2f b, v2f c) {
#if __has_builtin(__builtin_elementwise_fma)
    return __builtin_elementwise_fma(a, b, c);
#else
    v2f r; r.x = fmaf(a.x, b.x, c.x); r.y = fmaf(a.y, b.y, c.y); return r;
#endif
}

// ---------------- Phase A: out[b][t][h] = dot(x[b][t][:], W_in[h][:]) -------
// grid 4096 = 256 b x 16 tiles(128 rows), block 256 (4 waves, 32 rows each).
// 16KB x-tile staged coalesced into LDS; per-row reads are b128 broadcasts;
// stores coalesced. pk_fma packed; per-output accumulation order identical
// to previous passing kernels: a01.x=s0, a01.y=s1, a23.x=s2, a23.y=s3.
__global__ __launch_bounds__(256) void ctrnn_xproj(
    const float* __restrict__ x,
    const float* __restrict__ W_in,
    float* __restrict__ out)
{
    __shared__ alignas(16) float xs[128 * Dd];   // 16 KB
    const int tid  = threadIdx.x;
    const int lane = tid & 63;
    const int wave = tid >> 6;
    const int b    = blockIdx.x >> 4;
    const int tile = blockIdx.x & 15;
    const int t0   = tile * 128;

    // coalesced stage: 4096 floats = 1024 float4 = 4 rounds x 256 threads
    const float4* xsrc = reinterpret_cast<const float4*>(
        x + (size_t)b * Tt * Dd + (size_t)t0 * Dd);
    float4* xdst = reinterpret_cast<float4*>(xs);
#pragma unroll
    for (int r = 0; r < 4; ++r) xdst[r * 256 + tid] = xsrc[r * 256 + tid];

    // W row per lane as v2f pairs: w2[k] = W_in[lane][2k..2k+1]
    v2f w[16];
    const v2f* wrow = reinterpret_cast<const v2f*>(W_in + lane * Dd);
#pragma unroll
    for (int j = 0; j < 16; ++j) w[j] = wrow[j];

    __syncthreads();

    float* ob = out + (size_t)b * Tt * Hh + (size_t)t0 * Hh;
    const int lt0 = wave * 32;
#pragma unroll 2
    for (int i = 0; i < 32; ++i) {
        const float4* xr = reinterpret_cast<const float4*>(xs + (lt0 + i) * Dd);
        v2f a01 = {0.f, 0.f}, a23 = {0.f, 0.f};
#pragma unroll
        for (int j = 0; j < 8; ++j) {
            const float4 xv = xr[j];
            const v2f x01 = {xv.x, xv.y};
            const v2f x23 = {xv.z, xv.w};
            a01 = vfma2(w[2 * j + 0], x01, a01);   // elements 4j, 4j+1
            a23 = vfma2(w[2 * j + 1], x23, a23);   // elements 4j+2, 4j+3
        }
        ob[(size_t)(lt0 + i) * Hh + lane] = (a01.x + a01.y) + (a23.x + a23.y);
    }
}

// ---------------- Phase B: sequential recurrence, 1 wave per batch ----------
// Broadcast via LDS crossbar (ds_swizzle imm patterns), zero LDS array use.
// xp read from out rows (written by phase A), 8-deep register ring prefetch;
// row t overwritten with h_t after its xp is consumed.

// broadcast lane c (0..31) within each 32-lane half: and=0, or=c, xor=0
#define SWZB(srci, c) __int_as_float(__builtin_amdgcn_ds_swizzle((srci), ((c) << 5)))
// group: global columns c0..c0+3 live in half-src at offsets c0..c0+3
#define GRP(srci, c0, wi)                                            \
    {                                                                \
        v2f h01, h23;                                                \
        h01.x = SWZB(srci, (c0) + 0);                                \
        h01.y = SWZB(srci, (c0) + 1);                                \
        h23.x = SWZB(srci, (c0) + 2);                                \
        h23.y = SWZB(srci, (c0) + 3);                                \
        acc0 = vfma2(w[(wi) + 0], h01, acc0);                        \
        acc1 = vfma2(w[(wi) + 1], h23, acc1);                        \
    }

__global__ __launch_bounds__(64) void ctrnn_recur(
    const float* __restrict__ b_in,
    const float* __restrict__ W_hh,
    const float* __restrict__ b_hh,
    float* __restrict__ out)
{
    const int b    = blockIdx.x;
    const int lane = threadIdx.x;

    v2f w[Hh / 2];
    const v2f* wrow = reinterpret_cast<const v2f*>(W_hh + lane * Hh);
#pragma unroll
    for (int j = 0; j < Hh / 2; ++j) w[j] = wrow[j];
    const float cb = ALPHA * (b_in[lane] + b_hh[lane]);

    float* ob = out + (size_t)b * Tt * Hh + lane;

    float xp[8];
#pragma unroll
    for (int j = 0; j < 8; ++j) xp[j] = ob[(size_t)j * Hh];

    float* op       = ob;                   // store ptr (row t)
    const float* lp = ob + 8 * (size_t)Hh;  // refill ptr (row t+8)

    const int swap_src = lane ^ 32;         // partner lane in other half
    const bool lower   = (lane < 32);

    float hold = 0.0f;
    for (int t = 0; t < Tt; t += 8) {
#pragma unroll
        for (int j = 0; j < 8; ++j) {
            const int hb = __float_as_int(hold);
            const int yb = __shfl(hb, swap_src, 64);  // h[lane^32] (bpermute)
            // z_lo[l] = h[l&31]; z_hi[l] = h[32 | (l&31)]
            const int zlo = lower ? hb : yb;
            const int zhi = lower ? yb : hb;

            v2f acc0 = {0.f, 0.f}, acc1 = {0.f, 0.f};
            // columns 0..31 from zlo, 32..63 from zhi; identical accumulation
            // order to previous passing kernels: acc0 <- cols 4g,4g+1;
            // acc1 <- cols 4g+2,4g+3; g = 0..15.
            GRP(zlo,  0,  0) GRP(zlo,  4,  2) GRP(zlo,  8,  4) GRP(zlo, 12,  6)
            GRP(zlo, 16,  8) GRP(zlo, 20, 10) GRP(zlo, 24, 12) GRP(zlo, 28, 14)
            GRP(zhi,  0, 16) GRP(zhi,  4, 18) GRP(zhi,  8, 20) GRP(zhi, 12, 22)
            GRP(zhi, 16, 24) GRP(zhi, 20, 26) GRP(zhi, 24, 28) GRP(zhi, 28, 30)

            const v2f accs  = acc0 + acc1;
            const float sum = (accs.x + accs.y) + xp[j];
            const float hnew = fmaxf(fmaf(ALPHA, sum, fmaf(OMA, hold, cb)), 0.0f);

            *op = hnew;                    // overwrite xp row t+j with h
            op += Hh;
            hold = hnew;

            // refill ring 8 ahead (in-bounds past Tt: lands in hlast region,
            // value never consumed)
            xp[j] = *lp;
            lp += Hh;
        }
    }
    // h_last
    out[(size_t)Bb * Tt * Hh + (size_t)b * Hh + lane] = hold;
}

extern "C" void kernel_launch(void* const* d_in, const int* in_sizes, int n_in,
                              void* d_out, int out_size, void* d_ws, size_t ws_size,
                              hipStream_t stream) {
    const float* x    = (const float*)d_in[0];
    // d_in[1] = seq_lengths (int32): forward value is mask-independent.
    const float* W_in = (const float*)d_in[2];
    const float* b_in = (const float*)d_in[3];
    const float* W_hh = (const float*)d_in[4];
    const float* b_hh = (const float*)d_in[5];
    float* out = (float*)d_out;

    ctrnn_xproj<<<dim3(Bb * 16), dim3(256), 0, stream>>>(x, W_in, out);
    ctrnn_recur<<<dim3(Bb), dim3(64), 0, stream>>>(b_in, W_hh, b_hh, out);
}